// Round 4
// baseline (882.631 us; speedup 1.0000x reference)
//
#include <hip/hip_runtime.h>
#include <stdint.h>

// Problem constants (fixed by the reference)
#define TOKENS 8192
#define D_IN   1024
#define NEXP   8
#define D_OUT  1024
#define HDIM   2048
#define KBIG   (NEXP * HDIM)   // 16384

typedef __bf16 bf16x8 __attribute__((ext_vector_type(8)));
typedef __bf16 bf16x4 __attribute__((ext_vector_type(4)));
typedef float  f32x4  __attribute__((ext_vector_type(4)));

// ---------------------------------------------------------------------------
__device__ __forceinline__ void gload16(const void* g, void* l) {
  __builtin_amdgcn_global_load_lds(
      (const __attribute__((address_space(1))) void*)g,
      (__attribute__((address_space(3))) void*)l,
      16, 0, 0);
}

// ---------------------------------------------------------------------------
// Gating: gates[n][e] = softmax_e(x[n]·Wg[:,e] + bg[e]), fp32 exact.
__global__ void gate_kernel(const float* __restrict__ x,
                            const float* __restrict__ Wg,
                            const float* __restrict__ bg,
                            float* __restrict__ gates) {
  const int lane = threadIdx.x & 63;
  const int n = blockIdx.x * 4 + (threadIdx.x >> 6);
  float acc[NEXP];
#pragma unroll
  for (int e = 0; e < NEXP; ++e) acc[e] = 0.f;
  const float* xr = x + (size_t)n * D_IN;
  for (int d = lane; d < D_IN; d += 64) {
    float xv = xr[d];
    const float* wr = Wg + d * NEXP;
#pragma unroll
    for (int e = 0; e < NEXP; ++e) acc[e] += xv * wr[e];
  }
#pragma unroll
  for (int e = 0; e < NEXP; ++e) {
    float v = acc[e];
#pragma unroll
    for (int off = 32; off > 0; off >>= 1) v += __shfl_down(v, off);
    acc[e] = v;
  }
  if (lane == 0) {
    float mx = -1e30f;
#pragma unroll
    for (int e = 0; e < NEXP; ++e) { acc[e] += bg[e]; mx = fmaxf(mx, acc[e]); }
    float s = 0.f;
#pragma unroll
    for (int e = 0; e < NEXP; ++e) { acc[e] = expf(acc[e] - mx); s += acc[e]; }
    float inv = 1.f / s;
#pragma unroll
    for (int e = 0; e < NEXP; ++e) gates[n * NEXP + e] = acc[e] * inv;
  }
}

// ---------------------------------------------------------------------------
__global__ void cvt_x_kernel(const float* __restrict__ x, __bf16* __restrict__ xb) {
  const int stride = gridDim.x * blockDim.x;
  const int total4 = TOKENS * D_IN / 4;
  for (int i = blockIdx.x * blockDim.x + threadIdx.x; i < total4; i += stride) {
    float4 v = ((const float4*)x)[i];
    bf16x4 o;
    o[0] = (__bf16)v.x; o[1] = (__bf16)v.y; o[2] = (__bf16)v.z; o[3] = (__bf16)v.w;
    ((bf16x4*)xb)[i] = o;
  }
}

// ---------------------------------------------------------------------------
// Transpose-convert: in f32 W[e][k][n] -> Wt[e*ebase + n*ldo + k] (bf16).
__global__ void transpose_cvt_kernel(const float* __restrict__ W,
                                     __bf16* __restrict__ Wt,
                                     int K, int N, int ldo, size_t ebase) {
  __shared__ float tile[32][33];
  const int e = blockIdx.z;
  const float* Win = W + (size_t)e * K * N;
  __bf16* Wout = Wt + (size_t)e * ebase;
  const int n0 = blockIdx.x * 32;
  const int k0 = blockIdx.y * 32;
  const int tx = threadIdx.x & 31;
  const int ty = threadIdx.x >> 5;
#pragma unroll
  for (int r = ty; r < 32; r += 8)
    tile[r][tx] = Win[(size_t)(k0 + r) * N + n0 + tx];
  __syncthreads();
#pragma unroll
  for (int r = ty; r < 32; r += 8)
    Wout[(size_t)(n0 + r) * ldo + k0 + tx] = (__bf16)tile[tx][r];
}

// ---------------------------------------------------------------------------
// Two-barrier phase-pipelined GEMM: D = A[M][K] * B[N][K]^T, bf16, f32 accum.
// BK=32 K-tiles; 4-slot LDS ring; stage tile t+3 during t (race-free: slot
// (t+3)&3 was last read by tile t-1, whose reads completed before t-1's
// trailing barrier); counted vmcnt(2*LOADS) once per tile, never 0 mid-loop.
// Each sub-phase: reads, stage, barrier, lgkmcnt(0), 16-MFMA cluster, barrier.
// BK=32 => 64B LDS rows => ds_read_b128 at bank floor, NO swizzle needed.
// EPI 0: Hout[row][ocol0+col] = bf16(relu(D+bias[col]) * (scale_gate?g:1))
// EPI 1: Fout[row][col] (+)= (D + bias[col]) * gates[row][e]
// EPI 2: Fout[row][col]  =  D + sum_j gates[row][j]*b2[j][col]
template <int BM, int BN, int WM, int WN, int NSUB, int EPI>
__global__ __launch_bounds__(512, 2)
void gemm_pipe(const __bf16* __restrict__ A,
               const __bf16* __restrict__ Bbase, size_t Bstride_e,
               const float* __restrict__ biasbase, int bias_stride_e,
               const float* __restrict__ gates,
               const float* __restrict__ b2,
               int e0, int scale_gate, int first,
               __bf16* __restrict__ Hout, float* __restrict__ Fout,
               int M, int N, int K, int ldo, int ocol_stride_e) {
  constexpr int RM = BM / WM, RN = BN / WN;
  constexpr int FM = RM / 16, FN = RN / 16;
  constexpr int GM = FM / NSUB;                  // A-frags per sub-phase
  constexpr int SLOT  = (BM + BN) * 32;          // bf16 elems per ring slot
  constexpr int LOADS = (BM + BN) * 64 / 8192;   // gloads/thread per K-tile
  constexpr int LPS   = LOADS / NSUB;
  __shared__ alignas(16) __bf16 lds[4 * SLOT];

  const int tid  = threadIdx.x;
  const int lane = tid & 63;
  const int wave = tid >> 6;
  const int wr   = wave / WN;
  const int wc   = wave % WN;
  const int lrow = lane & 15;
  const int khi  = lane >> 4;
  const int e    = e0 + blockIdx.z;

  const __bf16* Bp   = Bbase + (size_t)e * Bstride_e;
  const float*  bias = biasbase + (size_t)e * bias_stride_e;
  const int     ocol0 = e * ocol_stride_e;

  // XCD-aware bijective block swizzle (nwg % 8 == 0 for all our grids)
  const int Gx   = gridDim.x;
  const int nwg  = Gx * gridDim.y;
  const int orig = blockIdx.y * Gx + blockIdx.x;
  const int wgid = (orig & 7) * (nwg >> 3) + (orig >> 3);
  const int bn0  = (wgid % Gx) * BN;
  const int bm0  = (wgid / Gx) * BM;

  // staging sources: slot byte o = i*8192 + tid*16; A region = BM*64 bytes
  const __bf16* gsrc[LOADS];
#pragma unroll
  for (int i = 0; i < LOADS; ++i) {
    int o    = i * 8192 + tid * 16;
    bool isA = (o < BM * 64);
    int oo   = isA ? o : (o - BM * 64);
    int row  = oo >> 6;
    int cb   = oo & 63;
    gsrc[i] = (isA ? A + (size_t)(bm0 + row) * K
                   : Bp + (size_t)(bn0 + row) * K) + (cb >> 1);
  }

  f32x4 acc[FM][FN];
#pragma unroll
  for (int m = 0; m < FM; ++m)
#pragma unroll
    for (int n = 0; n < FN; ++n) acc[m][n] = f32x4{0.f, 0.f, 0.f, 0.f};

  const int nk = K >> 5;   // requires nk >= 3 (all our K >= 1024)

  // prologue: stage tiles 0,1,2 into slots 0,1,2
#pragma unroll
  for (int pt = 0; pt < 3; ++pt)
#pragma unroll
    for (int i = 0; i < LOADS; ++i)
      gload16(gsrc[i] + (size_t)pt * 32, lds + pt * SLOT + i * 4096 + wave * 512);
  if constexpr (LOADS == 4) asm volatile("s_waitcnt vmcnt(8)" ::: "memory");
  else                      asm volatile("s_waitcnt vmcnt(6)" ::: "memory");
  asm volatile("s_barrier" ::: "memory");   // tile 0 visible to all waves

  for (int t = 0; t < nk; ++t) {
    const __bf16* As = lds + (t & 3) * SLOT;
    const __bf16* Bs = As + BM * 32;
    __bf16* ldst = lds + ((t + 3) & 3) * SLOT;
    const bool pf = (t + 3 < nk);
    bf16x8 bfr[FN];

#pragma unroll
    for (int q = 0; q < NSUB; ++q) {
      // --- ds reads for this sub-phase ---
      bf16x8 af[GM];
      if (q == 0) {
#pragma unroll
        for (int n = 0; n < FN; ++n)
          bfr[n] = *(const bf16x8*)&Bs[(wc * RN + n * 16 + lrow) * 32 + khi * 8];
      }
#pragma unroll
      for (int mi = 0; mi < GM; ++mi)
        af[mi] = *(const bf16x8*)&As[(wr * RM + (q * GM + mi) * 16 + lrow) * 32 + khi * 8];
      // --- stage portion of tile t+3 ---
      if (pf) {
#pragma unroll
        for (int j = 0; j < LPS; ++j) {
          const int i = q * LPS + j;
          gload16(gsrc[i] + (size_t)(t + 3) * 32, ldst + i * 4096 + wave * 512);
        }
      }
      asm volatile("s_barrier" ::: "memory");              // leading
      asm volatile("s_waitcnt lgkmcnt(0)" ::: "memory");
      __builtin_amdgcn_sched_barrier(0);                   // rule #18
      __builtin_amdgcn_s_setprio(1);
#pragma unroll
      for (int mi = 0; mi < GM; ++mi)
#pragma unroll
        for (int n = 0; n < FN; ++n)
          acc[q * GM + mi][n] = __builtin_amdgcn_mfma_f32_16x16x32_bf16(
              af[mi], bfr[n], acc[q * GM + mi][n], 0, 0, 0);
      __builtin_amdgcn_s_setprio(0);
      __builtin_amdgcn_sched_barrier(0);
      if (q == NSUB - 1 && t < nk - 1) {
        // ensure tile t+1 fully landed (all waves, with trailing barrier);
        // keep later tiles' loads in flight (counted, never 0 in steady state)
        if (t + 3 <= nk - 1) {
          if constexpr (LOADS == 4) asm volatile("s_waitcnt vmcnt(8)" ::: "memory");
          else                      asm volatile("s_waitcnt vmcnt(6)" ::: "memory");
        } else if (t + 2 <= nk - 1) {
          if constexpr (LOADS == 4) asm volatile("s_waitcnt vmcnt(4)" ::: "memory");
          else                      asm volatile("s_waitcnt vmcnt(3)" ::: "memory");
        } else {
          asm volatile("s_waitcnt vmcnt(0)" ::: "memory");
        }
      }
      asm volatile("s_barrier" ::: "memory");              // trailing
    }
  }

  // Epilogue. C/D frag: col = lane&15, row = (lane>>4)*4 + reg  [HW-verified]
#pragma unroll
  for (int m = 0; m < FM; ++m) {
    const int grow0 = bm0 + wr * RM + m * 16 + khi * 4;
    if constexpr (EPI == 0) {
      float g[4];
      if (scale_gate) {
#pragma unroll
        for (int r = 0; r < 4; ++r) g[r] = gates[(size_t)(grow0 + r) * NEXP + e];
      } else {
#pragma unroll
        for (int r = 0; r < 4; ++r) g[r] = 1.f;
      }
#pragma unroll
      for (int n = 0; n < FN; ++n) {
        const int lc = bn0 + wc * RN + n * 16 + lrow;
        const float bv = bias[lc];
        f32x4 a = acc[m][n];
#pragma unroll
        for (int r = 0; r < 4; ++r) {
          float v = a[r] + bv;
          v = v > 0.f ? v : 0.f;
          Hout[(size_t)(grow0 + r) * ldo + ocol0 + lc] = (__bf16)(v * g[r]);
        }
      }
    } else if constexpr (EPI == 1) {
      float g[4];
#pragma unroll
      for (int r = 0; r < 4; ++r) g[r] = gates[(size_t)(grow0 + r) * NEXP + e];
#pragma unroll
      for (int n = 0; n < FN; ++n) {
        const int lc = bn0 + wc * RN + n * 16 + lrow;
        const float bv = bias[lc];
        f32x4 a = acc[m][n];
#pragma unroll
        for (int r = 0; r < 4; ++r) {
          float v = (a[r] + bv) * g[r];
          float* o = Fout + (size_t)(grow0 + r) * ldo + lc;
          if (first) *o = v;
          else       *o += v;
        }
      }
    } else {
      float gv[4][NEXP];
#pragma unroll
      for (int r = 0; r < 4; ++r)
#pragma unroll
        for (int j = 0; j < NEXP; ++j)
          gv[r][j] = gates[(size_t)(grow0 + r) * NEXP + j];
#pragma unroll
      for (int n = 0; n < FN; ++n) {
        const int lc = bn0 + wc * RN + n * 16 + lrow;
        float b2v[NEXP];
#pragma unroll
        for (int j = 0; j < NEXP; ++j) b2v[j] = b2[j * N + lc];
        f32x4 a = acc[m][n];
#pragma unroll
        for (int r = 0; r < 4; ++r) {
          float bias2 = 0.f;
#pragma unroll
          for (int j = 0; j < NEXP; ++j) bias2 += gv[r][j] * b2v[j];
          Fout[(size_t)(grow0 + r) * ldo + lc] = a[r] + bias2;
        }
      }
    }
  }
}

// ---------------------------------------------------------------------------
extern "C" void kernel_launch(void* const* d_in, const int* in_sizes, int n_in,
                              void* d_out, int out_size, void* d_ws, size_t ws_size,
                              hipStream_t stream) {
  const float* x  = (const float*)d_in[0];
  const float* W1 = (const float*)d_in[1];
  const float* b1 = (const float*)d_in[2];
  const float* W2 = (const float*)d_in[3];
  const float* b2 = (const float*)d_in[4];
  const float* Wg = (const float*)d_in[5];
  const float* bg = (const float*)d_in[6];
  float* out = (float*)d_out;

  char* w = (char*)d_ws;
  float* gates = (float*)w;   w += (size_t)TOKENS * NEXP * 4;                 // 256 KB
  __bf16* xb   = (__bf16*)w;  w += (size_t)TOKENS * D_IN * 2;                 // 16 MB
  __bf16* w1t  = (__bf16*)w;  w += (size_t)NEXP * HDIM * D_IN * 2;            // 32 MB
  __bf16* w2t  = (__bf16*)w;  w += (size_t)NEXP * D_OUT * HDIM * 2;           // 32 MB
  __bf16* hbuf = (__bf16*)w;                                                  // 32 or 256 MB

  const size_t need_fused =
      (size_t)TOKENS * NEXP * 4 + (size_t)TOKENS * D_IN * 2 +
      (size_t)NEXP * HDIM * D_IN * 2 + (size_t)NEXP * D_OUT * HDIM * 2 +
      (size_t)TOKENS * KBIG * 2;
  const bool fused = (ws_size >= need_fused);

  gate_kernel<<<TOKENS / 4, 256, 0, stream>>>(x, Wg, bg, gates);
  cvt_x_kernel<<<2048, 256, 0, stream>>>(x, xb);
  transpose_cvt_kernel<<<dim3(HDIM / 32, D_IN / 32, NEXP), 256, 0, stream>>>(
      W1, w1t, D_IN, HDIM, D_IN, (size_t)HDIM * D_IN);

  if (fused) {
    // W2 [E][H][D_OUT] -> w2t[n][e*H + h]
    transpose_cvt_kernel<<<dim3(D_OUT / 32, HDIM / 32, NEXP), 256, 0, stream>>>(
        W2, w2t, HDIM, D_OUT, KBIG, (size_t)HDIM);
    gemm_pipe<256, 256, 2, 4, 2, 0><<<dim3(HDIM / 256, TOKENS / 256, NEXP), 512, 0, stream>>>(
        xb, w1t, (size_t)HDIM * D_IN, b1, HDIM, gates, nullptr,
        0, 1, 0, hbuf, nullptr, TOKENS, HDIM, D_IN, KBIG, HDIM);
    gemm_pipe<256, 128, 4, 2, 1, 2><<<dim3(D_OUT / 128, TOKENS / 256, 1), 512, 0, stream>>>(
        hbuf, w2t, 0, b2, 0, gates, b2,
        0, 0, 0, nullptr, out, TOKENS, D_OUT, KBIG, D_OUT, 0);
  } else {
    // W2 [E][H][D_OUT] -> w2t[e][n][h]
    transpose_cvt_kernel<<<dim3(D_OUT / 32, HDIM / 32, NEXP), 256, 0, stream>>>(
        W2, w2t, HDIM, D_OUT, HDIM, (size_t)D_OUT * HDIM);
    for (int e = 0; e < NEXP; ++e) {
      // GEMM1: 256x256 tile, grid (8,32) = 256 blocks (1/CU), per-wave 128x64
      gemm_pipe<256, 256, 2, 4, 2, 0><<<dim3(HDIM / 256, TOKENS / 256, 1), 512, 0, stream>>>(
          xb, w1t, (size_t)HDIM * D_IN, b1, HDIM, gates, nullptr,
          e, 0, 0, hbuf, nullptr, TOKENS, HDIM, D_IN, HDIM, 0);
      // GEMM2: 256x128 tile, grid (8,32) = 256 blocks, per-wave 64x64
      gemm_pipe<256, 128, 4, 2, 1, 1><<<dim3(D_OUT / 128, TOKENS / 256, 1), 512, 0, stream>>>(
          hbuf, w2t, (size_t)D_OUT * HDIM, b2, D_OUT, gates, nullptr,
          e, 0, (e == 0) ? 1 : 0, nullptr, out, TOKENS, D_OUT, HDIM, D_OUT, 0);
    }
  }
}

// Round 6
// 811.082 us; speedup vs baseline: 1.0882x; 1.0882x over previous
//
#include <hip/hip_runtime.h>
#include <stdint.h>

// Problem constants (fixed by the reference)
#define TOKENS 8192
#define D_IN   1024
#define NEXP   8
#define D_OUT  1024
#define HDIM   2048

typedef __bf16 bf16x8 __attribute__((ext_vector_type(8)));
typedef __bf16 bf16x4 __attribute__((ext_vector_type(4)));
typedef float  f32x4  __attribute__((ext_vector_type(4)));

// ---------------------------------------------------------------------------
__device__ __forceinline__ void gload16(const void* g, void* l) {
  __builtin_amdgcn_global_load_lds(
      (const __attribute__((address_space(1))) void*)g,
      (__attribute__((address_space(3))) void*)l,
      16, 0, 0);
}

template <int N>
__device__ __forceinline__ void waitv() {
  if constexpr (N == 0)      asm volatile("s_waitcnt vmcnt(0)" ::: "memory");
  else if constexpr (N == 1) asm volatile("s_waitcnt vmcnt(1)" ::: "memory");
  else if constexpr (N == 2) asm volatile("s_waitcnt vmcnt(2)" ::: "memory");
  else if constexpr (N == 3) asm volatile("s_waitcnt vmcnt(3)" ::: "memory");
  else if constexpr (N == 4) asm volatile("s_waitcnt vmcnt(4)" ::: "memory");
  else static_assert(N <= 4, "unsupported vmcnt");
}

// ---------------------------------------------------------------------------
// Gating: gates[n][e] = softmax_e(x[n]·Wg[:,e] + bg[e]), fp32 exact.
__global__ void gate_kernel(const float* __restrict__ x,
                            const float* __restrict__ Wg,
                            const float* __restrict__ bg,
                            float* __restrict__ gates) {
  const int lane = threadIdx.x & 63;
  const int n = blockIdx.x * 4 + (threadIdx.x >> 6);
  float acc[NEXP];
#pragma unroll
  for (int e = 0; e < NEXP; ++e) acc[e] = 0.f;
  const float* xr = x + (size_t)n * D_IN;
  for (int d = lane; d < D_IN; d += 64) {
    float xv = xr[d];
    const float* wr = Wg + d * NEXP;
#pragma unroll
    for (int e = 0; e < NEXP; ++e) acc[e] += xv * wr[e];
  }
#pragma unroll
  for (int e = 0; e < NEXP; ++e) {
    float v = acc[e];
#pragma unroll
    for (int off = 32; off > 0; off >>= 1) v += __shfl_down(v, off);
    acc[e] = v;
  }
  if (lane == 0) {
    float mx = -1e30f;
#pragma unroll
    for (int e = 0; e < NEXP; ++e) { acc[e] += bg[e]; mx = fmaxf(mx, acc[e]); }
    float s = 0.f;
#pragma unroll
    for (int e = 0; e < NEXP; ++e) { acc[e] = expf(acc[e] - mx); s += acc[e]; }
    float inv = 1.f / s;
#pragma unroll
    for (int e = 0; e < NEXP; ++e) gates[n * NEXP + e] = acc[e] * inv;
  }
}

// ---------------------------------------------------------------------------
__global__ void cvt_x_kernel(const float* __restrict__ x, __bf16* __restrict__ xb) {
  const int stride = gridDim.x * blockDim.x;
  const int total4 = TOKENS * D_IN / 4;
  for (int i = blockIdx.x * blockDim.x + threadIdx.x; i < total4; i += stride) {
    float4 v = ((const float4*)x)[i];
    bf16x4 o;
    o[0] = (__bf16)v.x; o[1] = (__bf16)v.y; o[2] = (__bf16)v.z; o[3] = (__bf16)v.w;
    ((bf16x4*)xb)[i] = o;
  }
}

// ---------------------------------------------------------------------------
// Transpose-convert: in f32 W[e][k][n] -> Wt[e][n][k] (bf16).
__global__ void transpose_cvt_kernel(const float* __restrict__ W,
                                     __bf16* __restrict__ Wt,
                                     int K, int N) {
  __shared__ float tile[32][33];
  const int e = blockIdx.z;
  const float* Win = W + (size_t)e * K * N;
  __bf16* Wout = Wt + (size_t)e * K * N;
  const int n0 = blockIdx.x * 32;
  const int k0 = blockIdx.y * 32;
  const int tx = threadIdx.x & 31;
  const int ty = threadIdx.x >> 5;
#pragma unroll
  for (int r = ty; r < 32; r += 8)
    tile[r][tx] = Win[(size_t)(k0 + r) * N + n0 + tx];
  __syncthreads();
#pragma unroll
  for (int r = ty; r < 32; r += 8)
    Wout[(size_t)(n0 + r) * K + k0 + tx] = (__bf16)tile[tx][r];
}

// ---------------------------------------------------------------------------
// Quadrant-phase ring-2 GEMM: D = A[M][K] * B[N][K]^T, bf16 in, f32 accum.
// BK=64 (128B LDS rows), XOR swizzle (row&7)<<4 (proven conflict-free).
// Per K-tile: 4 phases over (mq,nq) BLOCK-HALF quadrants. Phase = {frag
// ds_reads, stage one quarter of tile t+1 (order A0,B0,A1,B1), barrier,
// lgkm0+schedbar, setprio MFMA cluster, [counted vmcnt @p0/p3], barrier}.
//
// RACE FIX vs previous round: each wave's fragment rows are remapped so the
// phase quadrant coincides with the STAGED BLOCK HALF for ALL waves:
//   Arow(mq) = mq*(BM/2) + wr*(RM/2) + mi*16 + lrow
//   Bcol(nq) = nq*(BN/2) + wc*(RN/2) + ni*16 + lrow
// => mq/nq = 0 fragments live entirely in halves A0/B0 (landed: drained at
// t-1 p3 vmcnt(LA+LB) + barrier); mq/nq = 1 in A1/B1 (drained at p0 vmcnt(LA)
// + barrier, consumed at p1/p2). vmcnt never 0 mid-loop.
// (BM/2, RM/2 multiples of 8 => row&7 == lrow&7, swizzle parity preserved.)
// EPI 0: Hout[row][col] = bf16(relu(D + bias[col]))
// EPI 1: Fout[row][col] (+)= (D + bias[col]) * gates[row][e]
template <int BM, int BN, int WM, int WN, int EPI>
__global__ __launch_bounds__(512, 2)
void gemm_q4(const __bf16* __restrict__ A,
             const __bf16* __restrict__ Bbase, size_t Bstride_e,
             const float* __restrict__ biasbase, int bias_stride_e,
             const float* __restrict__ gates,
             int e, int first,
             __bf16* __restrict__ Hout, float* __restrict__ Fout,
             int M, int N, int K, int ldo) {
  constexpr int RM = BM / WM, RN = BN / WN;
  constexpr int FM = RM / 16, FN = RN / 16;
  constexpr int HM = FM / 2,  HN = FN / 2;
  constexpr int LA = BM / 128;          // gloads/thread per A-half
  constexpr int LB = BN / 128;          // gloads/thread per B-half
  constexpr int AELEM = BM * 64;        // A region elems per slot
  constexpr int SLOT  = (BM + BN) * 64; // elems per ring slot
  __shared__ alignas(16) __bf16 lds[2 * SLOT];

  const int tid  = threadIdx.x;
  const int lane = tid & 63;
  const int wave = tid >> 6;
  const int wr   = wave / WN;
  const int wc   = wave % WN;
  const int lrow = lane & 15;
  const int khi  = lane >> 4;
  const int sx   = (lrow & 7) << 3;     // read-side swizzle (elements)

  const __bf16* Bp   = Bbase + (size_t)e * Bstride_e;
  const float*  bias = biasbase + (size_t)e * bias_stride_e;

  // XCD-aware bijective block swizzle (nwg == 256 for all our grids)
  const int Gx   = gridDim.x;
  const int nwg  = Gx * gridDim.y;
  const int orig = blockIdx.y * Gx + blockIdx.x;
  const int wgid = (orig & 7) * (nwg >> 3) + (orig >> 3);
  const int bn0  = (wgid % Gx) * BN;
  const int bm0  = (wgid / Gx) * BM;

  // Pre-swizzled global sources: LDS byte o of region holds global column
  // byte (o&127) ^ ((row&7)<<4) of row (o>>7).
  const __bf16* srcA[2][LA];
  const __bf16* srcB[2][LB];
#pragma unroll
  for (int q = 0; q < 2; ++q) {
#pragma unroll
    for (int j = 0; j < LA; ++j) {
      int o   = q * (BM * 64) + j * 8192 + tid * 16;
      int row = o >> 7;
      int cb  = (o & 127) ^ ((row & 7) << 4);
      srcA[q][j] = A + (size_t)(bm0 + row) * K + (cb >> 1);
    }
#pragma unroll
    for (int j = 0; j < LB; ++j) {
      int o   = q * (BN * 64) + j * 8192 + tid * 16;
      int row = o >> 7;
      int cb  = (o & 127) ^ ((row & 7) << 4);
      srcB[q][j] = Bp + (size_t)(bn0 + row) * K + (cb >> 1);
    }
  }

  auto stageA = [&](int kt, int q, int s) {
#pragma unroll
    for (int j = 0; j < LA; ++j)
      gload16(srcA[q][j] + (size_t)kt * 64,
              lds + s * SLOT + q * (BM * 32) + j * 4096 + wave * 512);
  };
  auto stageB = [&](int kt, int q, int s) {
#pragma unroll
    for (int j = 0; j < LB; ++j)
      gload16(srcB[q][j] + (size_t)kt * 64,
              lds + s * SLOT + AELEM + q * (BN * 32) + j * 4096 + wave * 512);
  };

  f32x4 acc[FM][FN];
#pragma unroll
  for (int m = 0; m < FM; ++m)
#pragma unroll
    for (int n = 0; n < FN; ++n) acc[m][n] = f32x4{0.f, 0.f, 0.f, 0.f};

  bf16x8 af[HM][2];       // current mq-half A fragments
  bf16x8 bf[2][HN][2];    // B fragments, cached across the whole K-tile

  // FIXED mapping: fragment rows of half mq live in staged block-half mq.
  auto rdA = [&](const __bf16* As, int mq) {
#pragma unroll
    for (int mi = 0; mi < HM; ++mi)
#pragma unroll
      for (int kk = 0; kk < 2; ++kk)
        af[mi][kk] = *(const bf16x8*)
            &As[(size_t)(mq * (BM / 2) + wr * (RM / 2) + mi * 16 + lrow) * 64 +
                ((kk * 32 + khi * 8) ^ sx)];
  };
  auto rdB = [&](const __bf16* Bs, int nq) {
#pragma unroll
    for (int ni = 0; ni < HN; ++ni)
#pragma unroll
      for (int kk = 0; kk < 2; ++kk)
        bf[nq][ni][kk] = *(const bf16x8*)
            &Bs[(size_t)(nq * (BN / 2) + wc * (RN / 2) + ni * 16 + lrow) * 64 +
                ((kk * 32 + khi * 8) ^ sx)];
  };
  auto cluster = [&](int mq, int nq) {
    __builtin_amdgcn_s_setprio(1);
#pragma unroll
    for (int kk = 0; kk < 2; ++kk)
#pragma unroll
      for (int mi = 0; mi < HM; ++mi)
#pragma unroll
        for (int ni = 0; ni < HN; ++ni)
          acc[mq * HM + mi][nq * HN + ni] =
              __builtin_amdgcn_mfma_f32_16x16x32_bf16(
                  af[mi][kk], bf[nq][ni][kk], acc[mq * HM + mi][nq * HN + ni],
                  0, 0, 0);
    __builtin_amdgcn_s_setprio(0);
  };

#define BAR()   asm volatile("s_barrier" ::: "memory")
#define LGKM0() do { asm volatile("s_waitcnt lgkmcnt(0)" ::: "memory"); \
                     __builtin_amdgcn_sched_barrier(0); } while (0)

  const int nk = K >> 6;   // K-tiles of 64 (all our K in {1024, 2048})

  // prologue: stage all four halves of tile 0, drain once, barrier
  stageA(0, 0, 0); stageB(0, 0, 0); stageA(0, 1, 0); stageB(0, 1, 0);
  waitv<0>();
  BAR();

  for (int t = 0; t < nk; ++t) {
    const int s = t & 1;
    const __bf16* As = lds + s * SLOT;
    const __bf16* Bs = As + AELEM;
    const bool pf = (t + 1 < nk);

    // p0 : quadrant (0,0) ; stage A0(t+1)
    rdA(As, 0); rdB(Bs, 0);
    if (pf) stageA(t + 1, 0, s ^ 1);
    BAR(); LGKM0();
    cluster(0, 0);
    if (pf) waitv<LA>(); else waitv<0>();   // A1(t),B1(t) landed
    BAR();
    // p1 : quadrant (0,1) ; stage B0(t+1)
    rdB(Bs, 1);
    if (pf) stageB(t + 1, 0, s ^ 1);
    BAR(); LGKM0();
    cluster(0, 1);
    BAR();
    // p2 : quadrant (1,0) ; stage A1(t+1)
    rdA(As, 1);
    if (pf) stageA(t + 1, 1, s ^ 1);
    BAR(); LGKM0();
    cluster(1, 0);
    BAR();
    // p3 : quadrant (1,1) ; stage B1(t+1)
    if (pf) stageB(t + 1, 1, s ^ 1);
    BAR();
    cluster(1, 1);
    if (pf) waitv<LA + LB>(); else waitv<0>();  // A0,B0(t+1) landed
    BAR();
  }

#undef BAR
#undef LGKM0

  // Epilogue. C/D frag: col = lane&15, row = (lane>>4)*4 + reg  [HW-verified]
  // Row/col mapping matches the FIXED half-based fragment layout.
#pragma unroll
  for (int m = 0; m < FM; ++m) {
    const int grow0 = bm0 + (m / HM) * (BM / 2) + wr * (RM / 2) +
                      (m % HM) * 16 + khi * 4;
    if constexpr (EPI == 0) {
#pragma unroll
      for (int n = 0; n < FN; ++n) {
        const int gcol = bn0 + (n / HN) * (BN / 2) + wc * (RN / 2) +
                         (n % HN) * 16 + lrow;
        const float bv = bias[gcol];
        f32x4 a = acc[m][n];
#pragma unroll
        for (int r = 0; r < 4; ++r) {
          float v = a[r] + bv;
          v = v > 0.f ? v : 0.f;
          Hout[(size_t)(grow0 + r) * ldo + gcol] = (__bf16)v;
        }
      }
    } else {
      float g[4];
#pragma unroll
      for (int r = 0; r < 4; ++r) g[r] = gates[(size_t)(grow0 + r) * NEXP + e];
#pragma unroll
      for (int n = 0; n < FN; ++n) {
        const int gcol = bn0 + (n / HN) * (BN / 2) + wc * (RN / 2) +
                         (n % HN) * 16 + lrow;
        const float bv = bias[gcol];
        f32x4 a = acc[m][n];
#pragma unroll
        for (int r = 0; r < 4; ++r) {
          float v = (a[r] + bv) * g[r];
          float* o = Fout + (size_t)(grow0 + r) * ldo + gcol;
          if (first) *o = v;
          else       *o += v;
        }
      }
    }
  }
}

// ---------------------------------------------------------------------------
extern "C" void kernel_launch(void* const* d_in, const int* in_sizes, int n_in,
                              void* d_out, int out_size, void* d_ws, size_t ws_size,
                              hipStream_t stream) {
  const float* x  = (const float*)d_in[0];
  const float* W1 = (const float*)d_in[1];
  const float* b1 = (const float*)d_in[2];
  const float* W2 = (const float*)d_in[3];
  const float* b2 = (const float*)d_in[4];
  const float* Wg = (const float*)d_in[5];
  const float* bg = (const float*)d_in[6];
  float* out = (float*)d_out;

  // ws layout (~112 MB, proven safe)
  char* w = (char*)d_ws;
  float* gates = (float*)w;   w += (size_t)TOKENS * NEXP * 4;                 // 256 KB
  __bf16* xb   = (__bf16*)w;  w += (size_t)TOKENS * D_IN * 2;                 // 16 MB
  __bf16* w1t  = (__bf16*)w;  w += (size_t)NEXP * HDIM * D_IN * 2;            // 32 MB [E][H][D_IN]
  __bf16* w2t  = (__bf16*)w;  w += (size_t)NEXP * D_OUT * HDIM * 2;           // 32 MB [E][D_OUT][H]
  __bf16* hbuf = (__bf16*)w;                                                  // 32 MB [TOKENS][H]

  gate_kernel<<<TOKENS / 4, 256, 0, stream>>>(x, Wg, bg, gates);
  cvt_x_kernel<<<2048, 256, 0, stream>>>(x, xb);
  transpose_cvt_kernel<<<dim3(HDIM / 32, D_IN / 32, NEXP), 256, 0, stream>>>(
      W1, w1t, D_IN, HDIM);
  transpose_cvt_kernel<<<dim3(D_OUT / 32, HDIM / 32, NEXP), 256, 0, stream>>>(
      W2, w2t, HDIM, D_OUT);

  for (int e = 0; e < NEXP; ++e) {
    // GEMM1: 256x256 tile, waves 2Mx4N (per-wave 128x64), grid 8x32 = 256
    gemm_q4<256, 256, 2, 4, 0><<<dim3(HDIM / 256, TOKENS / 256), 512, 0, stream>>>(
        xb, w1t, (size_t)HDIM * D_IN, b1, HDIM, gates,
        e, 0, hbuf, nullptr, TOKENS, HDIM, D_IN, HDIM);
    // GEMM2: 256x128 tile, waves 4Mx2N (per-wave 64x64), grid 8x32 = 256
    gemm_q4<256, 128, 4, 2, 1><<<dim3(D_OUT / 128, TOKENS / 256), 512, 0, stream>>>(
        hbuf, w2t, (size_t)D_OUT * HDIM, b2, D_OUT, gates,
        e, (e == 0) ? 1 : 0, nullptr, out, TOKENS, D_OUT, HDIM, D_OUT);
  }
}

// Round 7
// 694.188 us; speedup vs baseline: 1.2715x; 1.1684x over previous
//
#include <hip/hip_runtime.h>
#include <stdint.h>

// Problem constants (fixed by the reference)
#define TOKENS 8192
#define D_IN   1024
#define NEXP   8
#define D_OUT  1024
#define HDIM   2048

typedef __bf16 bf16x8 __attribute__((ext_vector_type(8)));
typedef __bf16 bf16x4 __attribute__((ext_vector_type(4)));
typedef float  f32x4  __attribute__((ext_vector_type(4)));

// ---------------------------------------------------------------------------
__device__ __forceinline__ void gload16(const void* g, void* l) {
  __builtin_amdgcn_global_load_lds(
      (const __attribute__((address_space(1))) void*)g,
      (__attribute__((address_space(3))) void*)l,
      16, 0, 0);
}

template <int N>
__device__ __forceinline__ void waitv() {
  if constexpr (N == 0)      asm volatile("s_waitcnt vmcnt(0)" ::: "memory");
  else if constexpr (N == 1) asm volatile("s_waitcnt vmcnt(1)" ::: "memory");
  else if constexpr (N == 2) asm volatile("s_waitcnt vmcnt(2)" ::: "memory");
  else if constexpr (N == 3) asm volatile("s_waitcnt vmcnt(3)" ::: "memory");
  else if constexpr (N == 4) asm volatile("s_waitcnt vmcnt(4)" ::: "memory");
  else static_assert(N <= 4, "unsupported vmcnt");
}

// ---------------------------------------------------------------------------
// Gating: gates[n][e] = softmax_e(x[n]·Wg[:,e] + bg[e]), fp32 exact.
__global__ void gate_kernel(const float* __restrict__ x,
                            const float* __restrict__ Wg,
                            const float* __restrict__ bg,
                            float* __restrict__ gates) {
  const int lane = threadIdx.x & 63;
  const int n = blockIdx.x * 4 + (threadIdx.x >> 6);
  float acc[NEXP];
#pragma unroll
  for (int e = 0; e < NEXP; ++e) acc[e] = 0.f;
  const float* xr = x + (size_t)n * D_IN;
  for (int d = lane; d < D_IN; d += 64) {
    float xv = xr[d];
    const float* wr = Wg + d * NEXP;
#pragma unroll
    for (int e = 0; e < NEXP; ++e) acc[e] += xv * wr[e];
  }
#pragma unroll
  for (int e = 0; e < NEXP; ++e) {
    float v = acc[e];
#pragma unroll
    for (int off = 32; off > 0; off >>= 1) v += __shfl_down(v, off);
    acc[e] = v;
  }
  if (lane == 0) {
    float mx = -1e30f;
#pragma unroll
    for (int e = 0; e < NEXP; ++e) { acc[e] += bg[e]; mx = fmaxf(mx, acc[e]); }
    float s = 0.f;
#pragma unroll
    for (int e = 0; e < NEXP; ++e) { acc[e] = expf(acc[e] - mx); s += acc[e]; }
    float inv = 1.f / s;
#pragma unroll
    for (int e = 0; e < NEXP; ++e) gates[n * NEXP + e] = acc[e] * inv;
  }
}

// ---------------------------------------------------------------------------
__global__ void cvt_x_kernel(const float* __restrict__ x, __bf16* __restrict__ xb) {
  const int stride = gridDim.x * blockDim.x;
  const int total4 = TOKENS * D_IN / 4;
  for (int i = blockIdx.x * blockDim.x + threadIdx.x; i < total4; i += stride) {
    float4 v = ((const float4*)x)[i];
    bf16x4 o;
    o[0] = (__bf16)v.x; o[1] = (__bf16)v.y; o[2] = (__bf16)v.z; o[3] = (__bf16)v.w;
    ((bf16x4*)xb)[i] = o;
  }
}

// ---------------------------------------------------------------------------
// Transpose-convert: f32 W[e][k][n] -> bf16 Wt[slice = e/EPG][n][(e%EPG)*K + k]
// (EPG=1 gives the plain [e][n][k] layout.)
__global__ void transpose_cvt_kernel(const float* __restrict__ W,
                                     __bf16* __restrict__ Wt,
                                     int K, int N, int EPG) {
  __shared__ float tile[32][33];
  const int e = blockIdx.z;
  const int ldo = EPG * K;
  const float* Win = W + (size_t)e * K * N;
  __bf16* Wout = Wt + (size_t)(e / EPG) * N * ldo + (size_t)(e % EPG) * K;
  const int n0 = blockIdx.x * 32;
  const int k0 = blockIdx.y * 32;
  const int tx = threadIdx.x & 31;
  const int ty = threadIdx.x >> 5;
#pragma unroll
  for (int r = ty; r < 32; r += 8)
    tile[r][tx] = Win[(size_t)(k0 + r) * N + n0 + tx];
  __syncthreads();
#pragma unroll
  for (int r = ty; r < 32; r += 8)
    Wout[(size_t)(n0 + r) * ldo + k0 + tx] = (__bf16)tile[tx][r];
}

// ---------------------------------------------------------------------------
// Final merge: out[n][f] += (use_acc1 ? acc1[n][f] : 0) + sum_e g[n][e]*b2[e][f]
__global__ void merge_kernel(float* __restrict__ out,
                             const float* __restrict__ acc1,
                             const float* __restrict__ gates,
                             const float* __restrict__ b2,
                             int use_acc1) {
  const int idx = blockIdx.x * 256 + threadIdx.x;   // over TOKENS*D_OUT/4
  const int n = idx >> 8;
  const int fb = idx & 255;
  float4 o = ((const float4*)out)[idx];
  if (use_acc1) {
    float4 a = ((const float4*)acc1)[idx];
    o.x += a.x; o.y += a.y; o.z += a.z; o.w += a.w;
  }
  const float* g = gates + (size_t)n * NEXP;
#pragma unroll
  for (int e = 0; e < NEXP; ++e) {
    const float ge = g[e];
    float4 b = ((const float4*)(b2 + (size_t)e * D_OUT))[fb];
    o.x += ge * b.x; o.y += ge * b.y; o.z += ge * b.z; o.w += ge * b.w;
  }
  ((float4*)out)[idx] = o;
}

// ---------------------------------------------------------------------------
// Quadrant-phase ring-2 GEMM (R6-verified schedule): D = A[M][K]*B[N][K]^T,
// bf16 in, f32 accum. BK=64, XOR swizzle (row&7)<<4, block-half quadrant
// phases with counted vmcnt (never 0 mid-loop), XCD swizzle, setprio MFMA.
// z-dim: A += z*AZ, B += z*BZ (batching / parity).
// EPI 0 (GEMM1): Hout[row][z*OCZ + col] = bf16(relu(D + b1[e0+z][col]) *
//                gates[row][e0+z]),  Hout base += z*HZ.
// EPI 3 (GEMM2): F = (z ? F1 : F0);  F[row][col] (first ? = : +=) D.
template <int BM, int BN, int WM, int WN, int EPI>
__global__ __launch_bounds__(512, 2)
void moe_gemm(const __bf16* __restrict__ A, size_t AZ,
              const __bf16* __restrict__ B, size_t BZ,
              const float* __restrict__ b1g,
              const float* __restrict__ gates,
              int e0,
              __bf16* __restrict__ Hout, size_t HZ, int OCZ, int ldo,
              float* __restrict__ F0, float* __restrict__ F1,
              int first, int M, int N, int K) {
  constexpr int RM = BM / WM, RN = BN / WN;
  constexpr int FM = RM / 16, FN = RN / 16;
  constexpr int HM = FM / 2,  HN = FN / 2;
  constexpr int LA = BM / 128;          // gloads/thread per A-half
  constexpr int LB = BN / 128;          // gloads/thread per B-half
  constexpr int AELEM = BM * 64;        // A region elems per slot
  constexpr int SLOT  = (BM + BN) * 64; // elems per ring slot
  __shared__ alignas(16) __bf16 lds[2 * SLOT];

  const int tid  = threadIdx.x;
  const int lane = tid & 63;
  const int wave = tid >> 6;
  const int wr   = wave / WN;
  const int wc   = wave % WN;
  const int lrow = lane & 15;
  const int khi  = lane >> 4;
  const int sx   = (lrow & 7) << 3;     // read-side swizzle (elements)
  const int bz   = blockIdx.z;

  A += (size_t)bz * AZ;
  B += (size_t)bz * BZ;

  // XCD-aware bijective block swizzle (per-z nwg divisible by 8)
  const int Gx   = gridDim.x;
  const int nwg  = Gx * gridDim.y;
  const int orig = blockIdx.y * Gx + blockIdx.x;
  const int wgid = (orig & 7) * (nwg >> 3) + (orig >> 3);
  const int bn0  = (wgid % Gx) * BN;
  const int bm0  = (wgid / Gx) * BM;

  // Pre-swizzled global sources: LDS byte o of region holds global column
  // byte (o&127) ^ ((row&7)<<4) of row (o>>7).
  const __bf16* srcA[2][LA];
  const __bf16* srcB[2][LB];
#pragma unroll
  for (int q = 0; q < 2; ++q) {
#pragma unroll
    for (int j = 0; j < LA; ++j) {
      int o   = q * (BM * 64) + j * 8192 + tid * 16;
      int row = o >> 7;
      int cb  = (o & 127) ^ ((row & 7) << 4);
      srcA[q][j] = A + (size_t)(bm0 + row) * K + (cb >> 1);
    }
#pragma unroll
    for (int j = 0; j < LB; ++j) {
      int o   = q * (BN * 64) + j * 8192 + tid * 16;
      int row = o >> 7;
      int cb  = (o & 127) ^ ((row & 7) << 4);
      srcB[q][j] = B + (size_t)(bn0 + row) * K + (cb >> 1);
    }
  }

  auto stageA = [&](int kt, int q, int s) {
#pragma unroll
    for (int j = 0; j < LA; ++j)
      gload16(srcA[q][j] + (size_t)kt * 64,
              lds + s * SLOT + q * (BM * 32) + j * 4096 + wave * 512);
  };
  auto stageB = [&](int kt, int q, int s) {
#pragma unroll
    for (int j = 0; j < LB; ++j)
      gload16(srcB[q][j] + (size_t)kt * 64,
              lds + s * SLOT + AELEM + q * (BN * 32) + j * 4096 + wave * 512);
  };

  f32x4 acc[FM][FN];
#pragma unroll
  for (int m = 0; m < FM; ++m)
#pragma unroll
    for (int n = 0; n < FN; ++n) acc[m][n] = f32x4{0.f, 0.f, 0.f, 0.f};

  bf16x8 af[HM][2];       // current mq-half A fragments
  bf16x8 bf[2][HN][2];    // B fragments, cached across the K-tile

  // Fragment rows of half mq live in staged block-half mq (race-free).
  auto rdA = [&](const __bf16* As, int mq) {
#pragma unroll
    for (int mi = 0; mi < HM; ++mi)
#pragma unroll
      for (int kk = 0; kk < 2; ++kk)
        af[mi][kk] = *(const bf16x8*)
            &As[(size_t)(mq * (BM / 2) + wr * (RM / 2) + mi * 16 + lrow) * 64 +
                ((kk * 32 + khi * 8) ^ sx)];
  };
  auto rdB = [&](const __bf16* Bs, int nq) {
#pragma unroll
    for (int ni = 0; ni < HN; ++ni)
#pragma unroll
      for (int kk = 0; kk < 2; ++kk)
        bf[nq][ni][kk] = *(const bf16x8*)
            &Bs[(size_t)(nq * (BN / 2) + wc * (RN / 2) + ni * 16 + lrow) * 64 +
                ((kk * 32 + khi * 8) ^ sx)];
  };
  auto cluster = [&](int mq, int nq) {
    __builtin_amdgcn_s_setprio(1);
#pragma unroll
    for (int kk = 0; kk < 2; ++kk)
#pragma unroll
      for (int mi = 0; mi < HM; ++mi)
#pragma unroll
        for (int ni = 0; ni < HN; ++ni)
          acc[mq * HM + mi][nq * HN + ni] =
              __builtin_amdgcn_mfma_f32_16x16x32_bf16(
                  af[mi][kk], bf[nq][ni][kk], acc[mq * HM + mi][nq * HN + ni],
                  0, 0, 0);
    __builtin_amdgcn_s_setprio(0);
  };

#define BAR()   asm volatile("s_barrier" ::: "memory")
#define LGKM0() do { asm volatile("s_waitcnt lgkmcnt(0)" ::: "memory"); \
                     __builtin_amdgcn_sched_barrier(0); } while (0)

  const int nk = K >> 6;

  // prologue: stage all four halves of tile 0, drain once, barrier
  stageA(0, 0, 0); stageB(0, 0, 0); stageA(0, 1, 0); stageB(0, 1, 0);
  waitv<0>();
  BAR();

  for (int t = 0; t < nk; ++t) {
    const int s = t & 1;
    const __bf16* As = lds + s * SLOT;
    const __bf16* Bs = As + AELEM;
    const bool pf = (t + 1 < nk);

    // p0 : quadrant (0,0) ; stage A0(t+1)
    rdA(As, 0); rdB(Bs, 0);
    if (pf) stageA(t + 1, 0, s ^ 1);
    BAR(); LGKM0();
    cluster(0, 0);
    if (pf) waitv<LA>(); else waitv<0>();   // A1(t),B1(t) landed
    BAR();
    // p1 : quadrant (0,1) ; stage B0(t+1)
    rdB(Bs, 1);
    if (pf) stageB(t + 1, 0, s ^ 1);
    BAR(); LGKM0();
    cluster(0, 1);
    BAR();
    // p2 : quadrant (1,0) ; stage A1(t+1)
    rdA(As, 1);
    if (pf) stageA(t + 1, 1, s ^ 1);
    BAR(); LGKM0();
    cluster(1, 0);
    BAR();
    // p3 : quadrant (1,1) ; stage B1(t+1)
    if (pf) stageB(t + 1, 1, s ^ 1);
    BAR();
    cluster(1, 1);
    if (pf) waitv<LA + LB>(); else waitv<0>();  // A0,B0(t+1) landed
    BAR();
  }

#undef BAR
#undef LGKM0

  // Epilogue. C/D frag: col = lane&15, row = (lane>>4)*4 + reg  [HW-verified]
  const float* bias = (EPI == 0) ? b1g + (size_t)(e0 + bz) * HDIM : nullptr;
  const int ecol = e0 + bz;
  __bf16* Hp = (EPI == 0) ? Hout + (size_t)bz * HZ + (size_t)bz * OCZ : nullptr;
  float* F = (EPI == 3) ? (bz ? F1 : F0) : nullptr;

#pragma unroll
  for (int m = 0; m < FM; ++m) {
    const int grow0 = bm0 + (m / HM) * (BM / 2) + wr * (RM / 2) +
                      (m % HM) * 16 + khi * 4;
    if constexpr (EPI == 0) {
      float g[4];
#pragma unroll
      for (int r = 0; r < 4; ++r)
        g[r] = gates[(size_t)(grow0 + r) * NEXP + ecol];
#pragma unroll
      for (int n = 0; n < FN; ++n) {
        const int gcol = bn0 + (n / HN) * (BN / 2) + wc * (RN / 2) +
                         (n % HN) * 16 + lrow;
        const float bv = bias[gcol];
        f32x4 a = acc[m][n];
#pragma unroll
        for (int r = 0; r < 4; ++r) {
          float v = a[r] + bv;
          v = v > 0.f ? v : 0.f;
          Hp[(size_t)(grow0 + r) * ldo + gcol] = (__bf16)(v * g[r]);
        }
      }
    } else {
#pragma unroll
      for (int n = 0; n < FN; ++n) {
        const int gcol = bn0 + (n / HN) * (BN / 2) + wc * (RN / 2) +
                         (n % HN) * 16 + lrow;
        f32x4 a = acc[m][n];
#pragma unroll
        for (int r = 0; r < 4; ++r) {
          float* o = F + (size_t)(grow0 + r) * N + gcol;
          if (first) *o = a[r];
          else       *o += a[r];
        }
      }
    }
  }
}

// ---------------------------------------------------------------------------
extern "C" void kernel_launch(void* const* d_in, const int* in_sizes, int n_in,
                              void* d_out, int out_size, void* d_ws, size_t ws_size,
                              hipStream_t stream) {
  const float* x  = (const float*)d_in[0];
  const float* W1 = (const float*)d_in[1];
  const float* b1 = (const float*)d_in[2];
  const float* W2 = (const float*)d_in[3];
  const float* b2 = (const float*)d_in[4];
  const float* Wg = (const float*)d_in[5];
  const float* bg = (const float*)d_in[6];
  float* out = (float*)d_out;

  // ws layout
  char* w = (char*)d_ws;
  float* gates = (float*)w;   w += (size_t)TOKENS * NEXP * 4;       //   0.25 MB
  __bf16* xb   = (__bf16*)w;  w += (size_t)TOKENS * D_IN * 2;       //  16 MB
  __bf16* w1t  = (__bf16*)w;  w += (size_t)NEXP * HDIM * D_IN * 2;  //  32 MB
  __bf16* w2c  = (__bf16*)w;  w += (size_t)NEXP * D_OUT * HDIM * 2; //  32 MB
  const size_t base = (size_t)(w - (char*)d_ws);

  const size_t acc_b = (size_t)TOKENS * D_OUT * 4;  // 32 MB
  const size_t h1_b  = (size_t)TOKENS * HDIM * 2;   // 32 MB per expert
  const int G = (ws_size >= base + acc_b + 4 * h1_b) ? 4
              : (ws_size >= base + acc_b + 2 * h1_b) ? 2 : 1;

  float* acc1 = nullptr;
  if (G > 1) { acc1 = (float*)w; w += acc_b; }
  __bf16* hbuf = (__bf16*)w;

  const size_t WSLICE = (size_t)HDIM * D_IN;   // w1t per-expert elems

  gate_kernel<<<TOKENS / 4, 256, 0, stream>>>(x, Wg, bg, gates);
  cvt_x_kernel<<<2048, 256, 0, stream>>>(x, xb);
  transpose_cvt_kernel<<<dim3(HDIM / 32, D_IN / 32, NEXP), 256, 0, stream>>>(
      W1, w1t, D_IN, HDIM, 1);
  transpose_cvt_kernel<<<dim3(D_OUT / 32, HDIM / 32, NEXP), 256, 0, stream>>>(
      W2, w2c, HDIM, D_OUT, (G == 4) ? 2 : 1);

  if (G == 4) {
    // hbuf: 2 slices x [TOKENS][4096]; slice i2 holds experts {4d+2*i2, +1}
    for (int d = 0; d < 2; ++d) {
      for (int i2 = 0; i2 < 2; ++i2) {
        const int e0 = 4 * d + 2 * i2;
        moe_gemm<256, 256, 2, 4, 0><<<dim3(8, 32, 2), 512, 0, stream>>>(
            xb, 0, w1t + (size_t)e0 * WSLICE, WSLICE, b1, gates, e0,
            hbuf + (size_t)i2 * TOKENS * 4096, 0, HDIM, 2 * HDIM,
            nullptr, nullptr, 0, TOKENS, HDIM, D_IN);
      }
      moe_gemm<256, 256, 2, 4, 3><<<dim3(4, 32, 2), 512, 0, stream>>>(
          hbuf, (size_t)TOKENS * 4096,
          w2c + (size_t)(2 * d) * D_OUT * 4096, (size_t)D_OUT * 4096,
          nullptr, nullptr, 0, nullptr, 0, 0, 2 * HDIM,
          out, acc1, (d == 0) ? 1 : 0, TOKENS, D_OUT, 2 * HDIM);
    }
  } else if (G == 2) {
    // hbuf: 2 slices x [TOKENS][2048]; slice z holds expert 2d+z
    for (int d = 0; d < 4; ++d) {
      const int e0 = 2 * d;
      moe_gemm<256, 256, 2, 4, 0><<<dim3(8, 32, 2), 512, 0, stream>>>(
          xb, 0, w1t + (size_t)e0 * WSLICE, WSLICE, b1, gates, e0,
          hbuf, (size_t)TOKENS * HDIM, 0, HDIM,
          nullptr, nullptr, 0, TOKENS, HDIM, D_IN);
      moe_gemm<256, 256, 2, 4, 3><<<dim3(4, 32, 2), 512, 0, stream>>>(
          hbuf, (size_t)TOKENS * HDIM,
          w2c + (size_t)e0 * D_OUT * HDIM, (size_t)D_OUT * HDIM,
          nullptr, nullptr, 0, nullptr, 0, 0, HDIM,
          out, acc1, (d == 0) ? 1 : 0, TOKENS, D_OUT, HDIM);
    }
  } else {
    // G1 fallback: single expert at a time (R6 structure, gate-folded)
    for (int e = 0; e < NEXP; ++e) {
      moe_gemm<256, 256, 2, 4, 0><<<dim3(8, 32, 1), 512, 0, stream>>>(
          xb, 0, w1t + (size_t)e * WSLICE, 0, b1, gates, e,
          hbuf, 0, 0, HDIM,
          nullptr, nullptr, 0, TOKENS, HDIM, D_IN);
      moe_gemm<256, 128, 4, 2, 3><<<dim3(8, 32, 1), 512, 0, stream>>>(
          hbuf, 0, w2c + (size_t)e * D_OUT * HDIM, 0,
          nullptr, nullptr, 0, nullptr, 0, 0, HDIM,
          out, nullptr, (e == 0) ? 1 : 0, TOKENS, D_OUT, HDIM);
    }
  }

  merge_kernel<<<TOKENS, 256, 0, stream>>>(out, acc1, gates, b2, (G > 1) ? 1 : 0);
}

// Round 8
// 655.871 us; speedup vs baseline: 1.3457x; 1.0584x over previous
//
#include <hip/hip_runtime.h>
#include <stdint.h>

// Problem constants (fixed by the reference)
#define TOKENS 8192
#define D_IN   1024
#define NEXP   8
#define D_OUT  1024
#define HDIM   2048

typedef __bf16 bf16x8 __attribute__((ext_vector_type(8)));
typedef __bf16 bf16x4 __attribute__((ext_vector_type(4)));
typedef float  f32x4  __attribute__((ext_vector_type(4)));

// ---------------------------------------------------------------------------
__device__ __forceinline__ void gload16(const void* g, void* l) {
  __builtin_amdgcn_global_load_lds(
      (const __attribute__((address_space(1))) void*)g,
      (__attribute__((address_space(3))) void*)l,
      16, 0, 0);
}

template <int N>
__device__ __forceinline__ void waitv() {
  if constexpr (N == 0)      asm volatile("s_waitcnt vmcnt(0)" ::: "memory");
  else if constexpr (N == 1) asm volatile("s_waitcnt vmcnt(1)" ::: "memory");
  else if constexpr (N == 2) asm volatile("s_waitcnt vmcnt(2)" ::: "memory");
  else static_assert(N <= 2, "unsupported vmcnt");
}

// ---------------------------------------------------------------------------
// Fused gating + x->bf16 conversion. One wave per token.
// gates[n][e] = softmax_e(x[n]·Wg[:,e] + bg[e]) (fp32 exact); xb = bf16(x).
__global__ void gate_cvt_kernel(const float* __restrict__ x,
                                const float* __restrict__ Wg,
                                const float* __restrict__ bg,
                                float* __restrict__ gates,
                                __bf16* __restrict__ xb) {
  const int lane = threadIdx.x & 63;
  const int n = blockIdx.x * 4 + (threadIdx.x >> 6);
  float acc[NEXP];
#pragma unroll
  for (int e = 0; e < NEXP; ++e) acc[e] = 0.f;
  const float* xr = x + (size_t)n * D_IN;
  __bf16* xo = xb + (size_t)n * D_IN;
#pragma unroll 4
  for (int d0 = 0; d0 < D_IN; d0 += 64) {
    const int d = d0 + lane;
    float xv = xr[d];
    xo[d] = (__bf16)xv;
    const float* wr = Wg + d * NEXP;
#pragma unroll
    for (int e = 0; e < NEXP; ++e) acc[e] += xv * wr[e];
  }
#pragma unroll
  for (int e = 0; e < NEXP; ++e) {
    float v = acc[e];
#pragma unroll
    for (int off = 32; off > 0; off >>= 1) v += __shfl_down(v, off);
    acc[e] = v;
  }
  if (lane == 0) {
    float mx = -1e30f;
#pragma unroll
    for (int e = 0; e < NEXP; ++e) { acc[e] += bg[e]; mx = fmaxf(mx, acc[e]); }
    float s = 0.f;
#pragma unroll
    for (int e = 0; e < NEXP; ++e) { acc[e] = expf(acc[e] - mx); s += acc[e]; }
    float inv = 1.f / s;
#pragma unroll
    for (int e = 0; e < NEXP; ++e) gates[n * NEXP + e] = acc[e] * inv;
  }
}

// ---------------------------------------------------------------------------
// Transpose-convert: f32 W[e][k][n] -> bf16 Wt[slice = e/EPG][n][(e%EPG)*K + k]
__global__ void transpose_cvt_kernel(const float* __restrict__ W,
                                     __bf16* __restrict__ Wt,
                                     int K, int N, int EPG) {
  __shared__ float tile[32][33];
  const int e = blockIdx.z;
  const int ldo = EPG * K;
  const float* Win = W + (size_t)e * K * N;
  __bf16* Wout = Wt + (size_t)(e / EPG) * N * ldo + (size_t)(e % EPG) * K;
  const int n0 = blockIdx.x * 32;
  const int k0 = blockIdx.y * 32;
  const int tx = threadIdx.x & 31;
  const int ty = threadIdx.x >> 5;
#pragma unroll
  for (int r = ty; r < 32; r += 8)
    tile[r][tx] = Win[(size_t)(k0 + r) * N + n0 + tx];
  __syncthreads();
#pragma unroll
  for (int r = ty; r < 32; r += 8)
    Wout[(size_t)(n0 + r) * ldo + k0 + tx] = (__bf16)tile[tx][r];
}

// ---------------------------------------------------------------------------
// Final merge: out[n][f] += (use_acc1 ? acc1[n][f] : 0) + sum_e g[n][e]*b2[e][f]
__global__ void merge_kernel(float* __restrict__ out,
                             const float* __restrict__ acc1,
                             const float* __restrict__ gates,
                             const float* __restrict__ b2,
                             int use_acc1) {
  const int idx = blockIdx.x * 256 + threadIdx.x;   // over TOKENS*D_OUT/4
  const int n = idx >> 8;
  const int fb = idx & 255;
  float4 o = ((const float4*)out)[idx];
  if (use_acc1) {
    float4 a = ((const float4*)acc1)[idx];
    o.x += a.x; o.y += a.y; o.z += a.z; o.w += a.w;
  }
  const float* g = gates + (size_t)n * NEXP;
#pragma unroll
  for (int e = 0; e < NEXP; ++e) {
    const float ge = g[e];
    float4 b = ((const float4*)(b2 + (size_t)e * D_OUT))[fb];
    o.x += ge * b.x; o.y += ge * b.y; o.z += ge * b.z; o.w += ge * b.w;
  }
  ((float4*)out)[idx] = o;
}

// ---------------------------------------------------------------------------
// Single-slot rotating-quarter GEMM: D = A[M][K]*B[N][K]^T, bf16, f32 accum.
// BK=64, XOR swizzle (row&7)<<4. One LDS slot (64 KB @256^2 -> 2 blocks/CU).
// Quarters A0,B0,A1,B1 each have ONE reader phase (p0,p0,p2,p1) and are
// restaged 1+ phase after their read:
//   p0: read A0,B0 -> mma(0,0); stage A1(t)  ; wait vmcnt(LA)  [drain B1(t)]
//   p1: read B1    -> mma(0,1); stage A0(t+1); wait vmcnt(LA|0)[drain A1(t)]
//   p2: read A1    -> mma(1,0); stage B0(t+1); no wait
//   p3:            -> mma(1,1); stage B1(t+1); wait vmcnt(LB)  [drain A0,B0]
// FIFO-verified: in-flight 4-6 loads, never drained to 0 mid-loop.
// z-dim: A += z*AZ, B += z*BZ.
// EPI 0 (GEMM1): Hout[row][z*OCZ+col] = bf16(relu(D+b1[e0+z][col])*g[row][e0+z])
// EPI 3 (GEMM2): F = (z ? F1 : F0); F[row][col] (first ? = : +=) D.
template <int BM, int BN, int WM, int WN, int EPI>
__global__ __launch_bounds__(512, 2)
void moe_gemm(const __bf16* __restrict__ A, size_t AZ,
              const __bf16* __restrict__ B, size_t BZ,
              const float* __restrict__ b1g,
              const float* __restrict__ gates,
              int e0,
              __bf16* __restrict__ Hout, size_t HZ, int OCZ, int ldo,
              float* __restrict__ F0, float* __restrict__ F1,
              int first, int M, int N, int K) {
  constexpr int RM = BM / WM, RN = BN / WN;
  constexpr int FM = RM / 16, FN = RN / 16;
  constexpr int HM = FM / 2,  HN = FN / 2;
  constexpr int LA = BM / 128;          // gloads/thread per A-half
  constexpr int LB = BN / 128;          // gloads/thread per B-half
  constexpr int AELEM = BM * 64;        // A region elems
  __shared__ alignas(16) __bf16 lds[(BM + BN) * 64];   // ONE slot

  const int tid  = threadIdx.x;
  const int lane = tid & 63;
  const int wave = tid >> 6;
  const int wr   = wave / WN;
  const int wc   = wave % WN;
  const int lrow = lane & 15;
  const int khi  = lane >> 4;
  const int sx   = (lrow & 7) << 3;     // read-side swizzle (elements)
  const int bz   = blockIdx.z;

  A += (size_t)bz * AZ;
  B += (size_t)bz * BZ;

  // XCD-aware bijective block swizzle (per-z nwg divisible by 8)
  const int Gx   = gridDim.x;
  const int nwg  = Gx * gridDim.y;
  const int orig = blockIdx.y * Gx + blockIdx.x;
  const int wgid = (orig & 7) * (nwg >> 3) + (orig >> 3);
  const int bn0  = (wgid % Gx) * BN;
  const int bm0  = (wgid / Gx) * BM;

  // Pre-swizzled global sources: LDS byte o of region holds global column
  // byte (o&127) ^ ((row&7)<<4) of row (o>>7).
  const __bf16* srcA[2][LA];
  const __bf16* srcB[2][LB];
#pragma unroll
  for (int q = 0; q < 2; ++q) {
#pragma unroll
    for (int j = 0; j < LA; ++j) {
      int o   = q * (BM * 64) + j * 8192 + tid * 16;
      int row = o >> 7;
      int cb  = (o & 127) ^ ((row & 7) << 4);
      srcA[q][j] = A + (size_t)(bm0 + row) * K + (cb >> 1);
    }
#pragma unroll
    for (int j = 0; j < LB; ++j) {
      int o   = q * (BN * 64) + j * 8192 + tid * 16;
      int row = o >> 7;
      int cb  = (o & 127) ^ ((row & 7) << 4);
      srcB[q][j] = B + (size_t)(bn0 + row) * K + (cb >> 1);
    }
  }

  auto stageA = [&](int kt, int q) {
#pragma unroll
    for (int j = 0; j < LA; ++j)
      gload16(srcA[q][j] + (size_t)kt * 64,
              lds + q * (BM * 32) + j * 4096 + wave * 512);
  };
  auto stageB = [&](int kt, int q) {
#pragma unroll
    for (int j = 0; j < LB; ++j)
      gload16(srcB[q][j] + (size_t)kt * 64,
              lds + AELEM + q * (BN * 32) + j * 4096 + wave * 512);
  };

  f32x4 acc[FM][FN];
#pragma unroll
  for (int m = 0; m < FM; ++m)
#pragma unroll
    for (int n = 0; n < FN; ++n) acc[m][n] = f32x4{0.f, 0.f, 0.f, 0.f};

  bf16x8 af[HM][2];       // current mq-half A fragments
  bf16x8 bf[2][HN][2];    // B fragments, cached across the K-tile

  // Fragment rows of half mq live in staged block-half mq (race-free).
  auto rdA = [&](int mq) {
#pragma unroll
    for (int mi = 0; mi < HM; ++mi)
#pragma unroll
      for (int kk = 0; kk < 2; ++kk)
        af[mi][kk] = *(const bf16x8*)
            &lds[(size_t)(mq * (BM / 2) + wr * (RM / 2) + mi * 16 + lrow) * 64 +
                 ((kk * 32 + khi * 8) ^ sx)];
  };
  auto rdB = [&](int nq) {
#pragma unroll
    for (int ni = 0; ni < HN; ++ni)
#pragma unroll
      for (int kk = 0; kk < 2; ++kk)
        bf[nq][ni][kk] = *(const bf16x8*)
            &lds[AELEM +
                 (size_t)(nq * (BN / 2) + wc * (RN / 2) + ni * 16 + lrow) * 64 +
                 ((kk * 32 + khi * 8) ^ sx)];
  };
  auto cluster = [&](int mq, int nq) {
    __builtin_amdgcn_s_setprio(1);
#pragma unroll
    for (int kk = 0; kk < 2; ++kk)
#pragma unroll
      for (int mi = 0; mi < HM; ++mi)
#pragma unroll
        for (int ni = 0; ni < HN; ++ni)
          acc[mq * HM + mi][nq * HN + ni] =
              __builtin_amdgcn_mfma_f32_16x16x32_bf16(
                  af[mi][kk], bf[nq][ni][kk], acc[mq * HM + mi][nq * HN + ni],
                  0, 0, 0);
    __builtin_amdgcn_s_setprio(0);
  };

#define BAR()   asm volatile("s_barrier" ::: "memory")
#define LGKM0() do { asm volatile("s_waitcnt lgkmcnt(0)" ::: "memory"); \
                     __builtin_amdgcn_sched_barrier(0); } while (0)

  const int nk = K >> 6;   // >= 16 for all our shapes

  // prologue: stage A0(0), B0(0), B1(0); drain A0,B0 (leave B1 in flight)
  stageA(0, 0); stageB(0, 0); stageB(0, 1);
  waitv<LB>();
  BAR();

  for (int t = 0; t < nk; ++t) {
    const bool pf = (t + 1 < nk);

    // p0 : read A0,B0 ; mma(0,0) ; stage A1(t) ; drain B1(t)
    rdA(0); rdB(0);
    stageA(t, 1);
    BAR(); LGKM0();
    cluster(0, 0);
    waitv<LA>();
    BAR();
    // p1 : read B1 ; mma(0,1) ; stage A0(t+1) ; drain A1(t)
    rdB(1);
    if (pf) stageA(t + 1, 0);
    BAR(); LGKM0();
    cluster(0, 1);
    if (pf) waitv<LA>(); else waitv<0>();
    BAR();
    // p2 : read A1 ; mma(1,0) ; stage B0(t+1)
    rdA(1);
    if (pf) stageB(t + 1, 0);
    BAR(); LGKM0();
    cluster(1, 0);
    BAR();
    // p3 : mma(1,1) ; stage B1(t+1) ; drain A0,B0(t+1)
    if (pf) stageB(t + 1, 1);
    BAR();
    cluster(1, 1);
    if (pf) waitv<LB>();
    BAR();
  }

#undef BAR
#undef LGKM0

  // Epilogue. C/D frag: col = lane&15, row = (lane>>4)*4 + reg  [HW-verified]
  const float* bias = (EPI == 0) ? b1g + (size_t)(e0 + bz) * HDIM : nullptr;
  const int ecol = e0 + bz;
  __bf16* Hp = (EPI == 0) ? Hout + (size_t)bz * HZ + (size_t)bz * OCZ : nullptr;
  float* F = (EPI == 3) ? (bz ? F1 : F0) : nullptr;

#pragma unroll
  for (int m = 0; m < FM; ++m) {
    const int grow0 = bm0 + (m / HM) * (BM / 2) + wr * (RM / 2) +
                      (m % HM) * 16 + khi * 4;
    if constexpr (EPI == 0) {
      float g[4];
#pragma unroll
      for (int r = 0; r < 4; ++r)
        g[r] = gates[(size_t)(grow0 + r) * NEXP + ecol];
#pragma unroll
      for (int n = 0; n < FN; ++n) {
        const int gcol = bn0 + (n / HN) * (BN / 2) + wc * (RN / 2) +
                         (n % HN) * 16 + lrow;
        const float bv = bias[gcol];
        f32x4 a = acc[m][n];
#pragma unroll
        for (int r = 0; r < 4; ++r) {
          float v = a[r] + bv;
          v = v > 0.f ? v : 0.f;
          Hp[(size_t)(grow0 + r) * ldo + gcol] = (__bf16)(v * g[r]);
        }
      }
    } else {
#pragma unroll
      for (int n = 0; n < FN; ++n) {
        const int gcol = bn0 + (n / HN) * (BN / 2) + wc * (RN / 2) +
                         (n % HN) * 16 + lrow;
        f32x4 a = acc[m][n];
#pragma unroll
        for (int r = 0; r < 4; ++r) {
          float* o = F + (size_t)(grow0 + r) * N + gcol;
          if (first) *o = a[r];
          else       *o += a[r];
        }
      }
    }
  }
}

// ---------------------------------------------------------------------------
extern "C" void kernel_launch(void* const* d_in, const int* in_sizes, int n_in,
                              void* d_out, int out_size, void* d_ws, size_t ws_size,
                              hipStream_t stream) {
  const float* x  = (const float*)d_in[0];
  const float* W1 = (const float*)d_in[1];
  const float* b1 = (const float*)d_in[2];
  const float* W2 = (const float*)d_in[3];
  const float* b2 = (const float*)d_in[4];
  const float* Wg = (const float*)d_in[5];
  const float* bg = (const float*)d_in[6];
  float* out = (float*)d_out;

  // ws layout
  char* w = (char*)d_ws;
  float* gates = (float*)w;   w += (size_t)TOKENS * NEXP * 4;       //   0.25 MB
  __bf16* xb   = (__bf16*)w;  w += (size_t)TOKENS * D_IN * 2;       //  16 MB
  __bf16* w1t  = (__bf16*)w;  w += (size_t)NEXP * HDIM * D_IN * 2;  //  32 MB
  __bf16* w2c  = (__bf16*)w;  w += (size_t)NEXP * D_OUT * HDIM * 2; //  32 MB
  const size_t base = (size_t)(w - (char*)d_ws);

  const size_t acc_b = (size_t)TOKENS * D_OUT * 4;  // 32 MB
  const size_t h1_b  = (size_t)TOKENS * HDIM * 2;   // 32 MB per expert
  const int G = (ws_size >= base + acc_b + 4 * h1_b) ? 4
              : (ws_size >= base + acc_b + 2 * h1_b) ? 2 : 1;

  float* acc1 = nullptr;
  if (G > 1) { acc1 = (float*)w; w += acc_b; }
  __bf16* hbuf = (__bf16*)w;

  const size_t WSLICE = (size_t)HDIM * D_IN;   // w1t per-expert elems

  gate_cvt_kernel<<<TOKENS / 4, 256, 0, stream>>>(x, Wg, bg, gates, xb);
  transpose_cvt_kernel<<<dim3(HDIM / 32, D_IN / 32, NEXP), 256, 0, stream>>>(
      W1, w1t, D_IN, HDIM, 1);
  transpose_cvt_kernel<<<dim3(D_OUT / 32, HDIM / 32, NEXP), 256, 0, stream>>>(
      W2, w2c, HDIM, D_OUT, (G == 4) ? 2 : 1);

  if (G == 4) {
    // hbuf: 2 slices x [TOKENS][4096]; slice i2 holds experts {4d+2*i2, +1}
    for (int d = 0; d < 2; ++d) {
      for (int i2 = 0; i2 < 2; ++i2) {
        const int e0 = 4 * d + 2 * i2;
        moe_gemm<256, 256, 2, 4, 0><<<dim3(8, 32, 2), 512, 0, stream>>>(
            xb, 0, w1t + (size_t)e0 * WSLICE, WSLICE, b1, gates, e0,
            hbuf + (size_t)i2 * TOKENS * 4096, 0, HDIM, 2 * HDIM,
            nullptr, nullptr, 0, TOKENS, HDIM, D_IN);
      }
      moe_gemm<256, 256, 2, 4, 3><<<dim3(4, 32, 2), 512, 0, stream>>>(
          hbuf, (size_t)TOKENS * 4096,
          w2c + (size_t)(2 * d) * D_OUT * 4096, (size_t)D_OUT * 4096,
          nullptr, nullptr, 0, nullptr, 0, 0, 2 * HDIM,
          out, acc1, (d == 0) ? 1 : 0, TOKENS, D_OUT, 2 * HDIM);
    }
  } else if (G == 2) {
    // hbuf: 2 slices x [TOKENS][2048]; slice z holds expert 2d+z
    for (int d = 0; d < 4; ++d) {
      const int e0 = 2 * d;
      moe_gemm<256, 256, 2, 4, 0><<<dim3(8, 32, 2), 512, 0, stream>>>(
          xb, 0, w1t + (size_t)e0 * WSLICE, WSLICE, b1, gates, e0,
          hbuf, (size_t)TOKENS * HDIM, 0, HDIM,
          nullptr, nullptr, 0, TOKENS, HDIM, D_IN);
      moe_gemm<256, 256, 2, 4, 3><<<dim3(4, 32, 2), 512, 0, stream>>>(
          hbuf, (size_t)TOKENS * HDIM,
          w2c + (size_t)e0 * D_OUT * HDIM, (size_t)D_OUT * HDIM,
          nullptr, nullptr, 0, nullptr, 0, 0, HDIM,
          out, acc1, (d == 0) ? 1 : 0, TOKENS, D_OUT, HDIM);
    }
  } else {
    // G1 fallback: single expert at a time
    for (int e = 0; e < NEXP; ++e) {
      moe_gemm<256, 256, 2, 4, 0><<<dim3(8, 32, 1), 512, 0, stream>>>(
          xb, 0, w1t + (size_t)e * WSLICE, 0, b1, gates, e,
          hbuf, 0, 0, HDIM,
          nullptr, nullptr, 0, TOKENS, HDIM, D_IN);
      moe_gemm<256, 128, 4, 2, 3><<<dim3(8, 32, 1), 512, 0, stream>>>(
          hbuf, 0, w2c + (size_t)e * D_OUT * HDIM, 0,
          nullptr, nullptr, 0, nullptr, 0, 0, HDIM,
          out, nullptr, (e == 0) ? 1 : 0, TOKENS, D_OUT, HDIM);
    }
  }

  merge_kernel<<<TOKENS, 256, 0, stream>>>(out, acc1, gates, b2, (G > 1) ? 1 : 0);
}